// Round 3
// baseline (306.726 us; speedup 1.0000x reference)
//
#include <hip/hip_runtime.h>
#include <stdint.h>

#define DIM     128
#define NMEM    16384
#define NQ_TOT  2048
#define TQ      32                    // queries per WG
#define TN      64                    // mem rows per iter tile
#define NCHUNK  12                    // grid = 64 qrows x 12 chunks = 768 = 3/CU
#define QROWS   (NQ_TOT / TQ)         // 64
#define SHIFT   30.0f

typedef short s8v __attribute__((ext_vector_type(8)));
typedef float f4v __attribute__((ext_vector_type(4)));

// ---- workspace layout (bytes) ----
#define OFF_MHI   0u
#define OFF_MLO   (4u << 20)
#define OFF_MHIT  (8u << 20)
#define OFF_NUM   (12u << 20)
#define OFF_DEN   (OFF_NUM + (NCHUNK * NQ_TOT * DIM * 4u))
#define WS_NEED   ((size_t)(OFF_DEN + NCHUNK * NQ_TOT * 4u))

__device__ __forceinline__ uint16_t f2bf(float x) {
    uint32_t u = __float_as_uint(x);
    uint32_t r = u + 0x7fffu + ((u >> 16) & 1u);   // RNE
    return (uint16_t)(r >> 16);
}
__device__ __forceinline__ float bf2f(uint16_t h) {
    return __uint_as_float(((uint32_t)h) << 16);
}

// ============ pre-pass: fp32 memory -> bf16 hi/lo + transposed hi ============
__global__ __launch_bounds__(256)
void convert_kernel(const float* __restrict__ mem, uint16_t* __restrict__ mhi,
                    uint16_t* __restrict__ mlo, uint16_t* __restrict__ mhit) {
    __shared__ uint16_t T[DIM * 64];           // [d][n] 16 KB
    const int b  = blockIdx.x;                 // 256 blocks x 64 rows
    const int t  = threadIdx.x;
    const int n0 = b * 64;
    #pragma unroll
    for (int k = 0; k < 8; ++k) {
        const int idx4 = t + k * 256;          // float4 index within 64x128 tile
        const int r    = idx4 >> 5;
        const int c4   = idx4 & 31;
        const float4 v = ((const float4*)(mem + (size_t)(n0 + r) * DIM))[c4];
        const uint16_t h0 = f2bf(v.x), h1 = f2bf(v.y), h2 = f2bf(v.z), h3 = f2bf(v.w);
        *(ushort4*)&mhi[(size_t)(n0 + r) * DIM + c4 * 4] = make_ushort4(h0, h1, h2, h3);
        *(ushort4*)&mlo[(size_t)(n0 + r) * DIM + c4 * 4] =
            make_ushort4(f2bf(v.x - bf2f(h0)), f2bf(v.y - bf2f(h1)),
                         f2bf(v.z - bf2f(h2)), f2bf(v.w - bf2f(h3)));
        T[(c4 * 4 + 0) * 64 + r] = h0;
        T[(c4 * 4 + 1) * 64 + r] = h1;
        T[(c4 * 4 + 2) * 64 + r] = h2;
        T[(c4 * 4 + 3) * 64 + r] = h3;
    }
    __syncthreads();
    {
        const int d = t >> 1, h = t & 1;
        ushort4* dst = (ushort4*)&mhit[(size_t)d * NMEM + n0 + h * 32];
        const ushort4* src = (const ushort4*)&T[d * 64 + h * 32];
        #pragma unroll
        for (int k = 0; k < 8; ++k) dst[k] = src[k];
    }
}

// ============ main: S^T = M*Q^T via MFMA -> exp in-reg -> PV from registers ==
__global__ __launch_bounds__(256, 3)
void attn_kernel(const float* __restrict__ query,
                 const uint16_t* __restrict__ mhi,
                 const uint16_t* __restrict__ mlo,
                 const uint16_t* __restrict__ mhit,
                 float* __restrict__ num, float* __restrict__ den) {
    __shared__ uint16_t MsHi[TN * DIM];  // [n][chunk^swz] 16 KB
    __shared__ uint16_t MsLo[TN * DIM];  // 16 KB
    __shared__ uint16_t MsT [DIM * TN];  // [d][ngrp^swz]  16 KB (reused as fp32 Obuf)
    __shared__ float    Red [4 * TQ];    // 512 B

    const int tid   = threadIdx.x;
    const int wv    = tid >> 6;
    const int lane  = tid & 63;
    const int l16   = lane & 15;
    const int quad  = lane >> 4;
    const int qrow  = blockIdx.x & (QROWS - 1);
    const int chunk = blockIdx.x >> 6;
    const int q0    = qrow * TQ;
    // chunk c owns tiles [c*21 + min(c,4), +21 or +22): 4*22 + 8*21 = 256 tiles
    const int tile0  = chunk * 21 + (chunk < 4 ? chunk : 4);
    const int ntiles = 21 + (chunk < 4 ? 1 : 0);

    // ---- Q fragments (B-operand: B[k=d][col=q], lane: q=l16, d=quad*8+j) ----
    s8v qh[2][4], ql[2][4];
    #pragma unroll
    for (int qt = 0; qt < 2; ++qt) {
        const float* qp = query + (size_t)(q0 + qt * 16 + l16) * DIM + quad * 8;
        #pragma unroll
        for (int ks = 0; ks < 4; ++ks) {
            const float4 a = *(const float4*)(qp + ks * 32);
            const float4 b = *(const float4*)(qp + ks * 32 + 4);
            const float f[8] = {a.x, a.y, a.z, a.w, b.x, b.y, b.z, b.w};
            s8v vh, vl;
            #pragma unroll
            for (int j = 0; j < 8; ++j) {
                const uint16_t hh = f2bf(f[j]);
                vh[j] = (short)hh;
                vl[j] = (short)f2bf(f[j] - bf2f(hh));
            }
            qh[qt][ks] = vh;
            ql[qt][ks] = vl;
        }
    }

    f4v oacc[2][8];                      // O-partial[q32][d128] per wave (its n)
    float dacc[2];
    #pragma unroll
    for (int qt = 0; qt < 2; ++qt) {
        dacc[qt] = 0.f;
        #pragma unroll
        for (int dt = 0; dt < 8; ++dt) oacc[qt][dt] = (f4v){0.f, 0.f, 0.f, 0.f};
    }

    const int srcA = ((quad & 1) << 5) + l16;   // P-shfl sources (valid quads 0,1)
    const int srcB = srcA + 16;
    const bool av  = quad < 2;

    for (int it = 0; it < ntiles; ++it) {
        const int n0 = (tile0 + it) * TN;
        __syncthreads();                 // prev iter done with tiles

        // ---- stage 48 x 16B global_load_lds, 12 per wave ----
        #pragma unroll
        for (int ii = 0; ii < 12; ++ii) {
            const int id = wv * 12 + ii;
            if (id < 16) {
                const int s = id * 64 + lane;
                const int r = s >> 4, c = (s & 15) ^ (r & 15);
                const uint16_t* g = mhi + (size_t)(n0 + r) * DIM + c * 8;
                __builtin_amdgcn_global_load_lds(
                    (const __attribute__((address_space(1))) void*)g,
                    (__attribute__((address_space(3))) void*)&MsHi[id * 512], 16, 0, 0);
            } else if (id < 32) {
                const int j = id - 16;
                const int s = j * 64 + lane;
                const int r = s >> 4, c = (s & 15) ^ (r & 15);
                const uint16_t* g = mlo + (size_t)(n0 + r) * DIM + c * 8;
                __builtin_amdgcn_global_load_lds(
                    (const __attribute__((address_space(1))) void*)g,
                    (__attribute__((address_space(3))) void*)&MsLo[j * 512], 16, 0, 0);
            } else {
                const int j = id - 32;
                const int s = j * 64 + lane;
                const int d = s >> 3, h = (s & 7) ^ (d & 7);
                const uint16_t* g = mhit + (size_t)d * NMEM + n0 + h * 8;
                __builtin_amdgcn_global_load_lds(
                    (const __attribute__((address_space(1))) void*)g,
                    (__attribute__((address_space(3))) void*)&MsT[j * 512], 16, 0, 0);
            }
        }
        __syncthreads();                 // staging visible

        // ---- S^T: A = M rows (wave's 16 n), B = Q regs ----
        f4v sacc[2];
        sacc[0] = (f4v){0.f, 0.f, 0.f, 0.f};
        sacc[1] = (f4v){0.f, 0.f, 0.f, 0.f};
        const int nrow = wv * 16 + l16;
        #pragma unroll
        for (int ks = 0; ks < 4; ++ks) {
            const int slot = (((ks * 4 + quad) ^ l16) << 3);
            const s8v ah = *(const s8v*)&MsHi[nrow * DIM + slot];
            const s8v al = *(const s8v*)&MsLo[nrow * DIM + slot];
            #pragma unroll
            for (int qt = 0; qt < 2; ++qt) {
                sacc[qt] = __builtin_amdgcn_mfma_f32_16x16x32_bf16(ah, qh[qt][ks], sacc[qt], 0, 0, 0);
                sacc[qt] = __builtin_amdgcn_mfma_f32_16x16x32_bf16(al, qh[qt][ks], sacc[qt], 0, 0, 0);
                sacc[qt] = __builtin_amdgcn_mfma_f32_16x16x32_bf16(ah, ql[qt][ks], sacc[qt], 0, 0, 0);
            }
        }

        // ---- exp (bf16-rounded, num/den consistent) + pack ----
        int pk[2][2];
        #pragma unroll
        for (int qt = 0; qt < 2; ++qt) {
            uint16_t pb[4];
            #pragma unroll
            for (int rg = 0; rg < 4; ++rg) {
                const float p = __expf(sacc[qt][rg] - SHIFT);
                pb[rg] = f2bf(p);
                dacc[qt] += bf2f(pb[rg]);
            }
            pk[qt][0] = (int)((uint32_t)pb[0] | ((uint32_t)pb[1] << 16));
            pk[qt][1] = (int)((uint32_t)pb[2] | ((uint32_t)pb[3] << 16));
        }

        // ---- A-frags for PV: intra-wave shfl permute + zero-pad k>=16 ----
        s8v pfrag[2];
        #pragma unroll
        for (int qt = 0; qt < 2; ++qt) {
            const int v0 = __shfl(pk[qt][0], srcA, 64);
            const int v1 = __shfl(pk[qt][1], srcA, 64);
            const int v2 = __shfl(pk[qt][0], srcB, 64);
            const int v3 = __shfl(pk[qt][1], srcB, 64);
            union { s8v v; int u[4]; } pf;
            pf.u[0] = av ? v0 : 0;
            pf.u[1] = av ? v1 : 0;
            pf.u[2] = av ? v2 : 0;
            pf.u[3] = av ? v3 : 0;
            pfrag[qt] = pf.v;
        }

        // ---- PV: O[q][d] += P[q][n] V[n][d], B = V^T fragments from MsT ----
        const int hT = wv * 2 + (quad & 1);
        #pragma unroll
        for (int dt = 0; dt < 8; ++dt) {
            const int d = dt * 16 + l16;
            const s8v bt = *(const s8v*)&MsT[d * TN + ((hT ^ (d & 7)) << 3)];
            oacc[0][dt] = __builtin_amdgcn_mfma_f32_16x16x32_bf16(pfrag[0], bt, oacc[0][dt], 0, 0, 0);
            oacc[1][dt] = __builtin_amdgcn_mfma_f32_16x16x32_bf16(pfrag[1], bt, oacc[1][dt], 0, 0, 0);
        }
    }

    // ---- denominator: reduce over quads (n-split within wave already summed) ----
    #pragma unroll
    for (int qt = 0; qt < 2; ++qt) {
        dacc[qt] += __shfl_xor(dacc[qt], 16, 64);
        dacc[qt] += __shfl_xor(dacc[qt], 32, 64);
    }
    if (quad == 0) {
        Red[wv * TQ + l16]      = dacc[0];
        Red[wv * TQ + 16 + l16] = dacc[1];
    }

    // ---- O merge across waves via LDS (reuse MsT as fp32 buffer) ----
    float* Obuf = (float*)MsT;           // 32 q x 128 d x 4B = 16 KB
    __syncthreads();                     // loop done with MsT; Red written
    for (int w = 0; w < 4; ++w) {
        if (wv == w) {
            #pragma unroll
            for (int qt = 0; qt < 2; ++qt)
                #pragma unroll
                for (int dt = 0; dt < 8; ++dt)
                    #pragma unroll
                    for (int rg = 0; rg < 4; ++rg) {
                        const int idx = (qt * 16 + quad * 4 + rg) * DIM + dt * 16 + l16;
                        if (w == 0) Obuf[idx] = oacc[qt][dt][rg];
                        else        Obuf[idx] += oacc[qt][dt][rg];
                    }
        }
        __syncthreads();
    }

    // ---- write den + num partials ----
    if (tid < TQ) {
        const float ds = Red[tid] + Red[TQ + tid] + Red[2 * TQ + tid] + Red[3 * TQ + tid];
        den[chunk * NQ_TOT + q0 + tid] = ds;
    }
    #pragma unroll
    for (int k = 0; k < 4; ++k) {
        const int f = tid + k * 256;     // float4 index, 1024 total
        const int q = f >> 5;
        const float4 v = ((const float4*)Obuf)[f];
        ((float4*)(num + ((size_t)chunk * NQ_TOT + q0 + q) * DIM))[f & 31] = v;
    }
}

// ============ final reduce over chunks + normalize ============
__global__ __launch_bounds__(256)
void reduce_kernel(const float* __restrict__ num, const float* __restrict__ den,
                   float* __restrict__ out) {
    const int idx = blockIdx.x * 256 + threadIdx.x;   // 262144
    const int q = idx >> 7;
    float ns = 0.f, ds = 0.f;
    #pragma unroll
    for (int c = 0; c < NCHUNK; ++c) {
        ns += num[(size_t)c * NQ_TOT * DIM + idx];
        ds += den[c * NQ_TOT + q];
    }
    out[idx] = ns / ds;
}

// ============ fallback (round-1 fp32 kernel) if ws too small ============
#define FTQ 8
#define FTN 64
#define FNTILES (NMEM / FTN)
#define FBLOCK 512
#define MPAD 132
#define PPAD 68

__global__ __launch_bounds__(FBLOCK, 2)
void sparse_attn_fp32(const float* __restrict__ query,
                      const float* __restrict__ memory,
                      float* __restrict__ out) {
    __shared__ float Qs[FTQ * MPAD];
    __shared__ float Ms[FTN * MPAD];
    __shared__ float Psh[FTQ * PPAD];
    __shared__ float Rd[FTQ * PPAD];
    const int tid = threadIdx.x;
    const int q = tid & 7, rest = tid >> 3;
    const int ng = rest, dg = rest & 31, half = rest >> 5;
    const long q0 = (long)blockIdx.x * FTQ;
    if (tid < FTQ * DIM / 4) {
        const float4 v = ((const float4*)(query + q0 * DIM))[tid];
        *(float4*)&Qs[(tid >> 5) * MPAD + ((tid & 31) << 2)] = v;
    }
    float4 pf[4];
    {
        const float4* msrc = (const float4*)memory;
        #pragma unroll
        for (int k = 0; k < 4; ++k) pf[k] = msrc[tid + k * FBLOCK];
    }
    float4 acc = make_float4(0.f, 0.f, 0.f, 0.f);
    float l_part = 0.f;
    for (int t = 0; t < FNTILES; ++t) {
        __syncthreads();
        #pragma unroll
        for (int k = 0; k < 4; ++k) {
            const int f4 = tid + k * FBLOCK;
            *(float4*)&Ms[(f4 >> 5) * MPAD + ((f4 & 31) << 2)] = pf[k];
        }
        __syncthreads();
        if (t + 1 < FNTILES) {
            const float4* msrc = (const float4*)(memory + (long)(t + 1) * FTN * DIM);
            #pragma unroll
            for (int k = 0; k < 4; ++k) pf[k] = msrc[tid + k * FBLOCK];
        }
        float4 s4 = make_float4(0.f, 0.f, 0.f, 0.f);
        const float* qrow = &Qs[q * MPAD];
        const float* mrow = &Ms[ng * MPAD];
        #pragma unroll
        for (int j = 0; j < 32; ++j) {
            const float4 qv = *(const float4*)&qrow[j * 4];
            const float4 mv = *(const float4*)&mrow[j * 4];
            s4.x += qv.x * mv.x; s4.y += qv.y * mv.y;
            s4.z += qv.z * mv.z; s4.w += qv.w * mv.w;
        }
        const float p = __expf(((s4.x + s4.y) + (s4.z + s4.w)) - SHIFT);
        Psh[q * PPAD + ng] = p;
        l_part += p;
        __syncthreads();
        #pragma unroll
        for (int n = 0; n < 32; ++n) {
            const int nn = half * 32 + n;
            const float pw = Psh[q * PPAD + nn];
            const float4 mv = *(const float4*)&Ms[nn * MPAD + dg * 4];
            acc.x += pw * mv.x; acc.y += pw * mv.y;
            acc.z += pw * mv.z; acc.w += pw * mv.w;
        }
    }
    __syncthreads();
    Rd[q * PPAD + rest] = l_part;
    if (half == 1) *(float4*)&Ms[q * MPAD + dg * 4] = acc;
    __syncthreads();
    if (half == 0) {
        const float4 o2 = *(const float4*)&Ms[q * MPAD + dg * 4];
        float l = 0.f;
        #pragma unroll 8
        for (int i = 0; i < 64; ++i) l += Rd[q * PPAD + i];
        const float inv = 1.0f / l;
        float4 o;
        o.x = (acc.x + o2.x) * inv; o.y = (acc.y + o2.y) * inv;
        o.z = (acc.z + o2.z) * inv; o.w = (acc.w + o2.w) * inv;
        *(float4*)(out + (q0 + q) * DIM + dg * 4) = o;
    }
}

extern "C" void kernel_launch(void* const* d_in, const int* in_sizes, int n_in,
                              void* d_out, int out_size, void* d_ws, size_t ws_size,
                              hipStream_t stream) {
    const float* query  = (const float*)d_in[0];
    const float* memory = (const float*)d_in[1];
    float* out = (float*)d_out;
    if (ws_size >= WS_NEED) {
        uint16_t* mhi  = (uint16_t*)((char*)d_ws + OFF_MHI);
        uint16_t* mlo  = (uint16_t*)((char*)d_ws + OFF_MLO);
        uint16_t* mhit = (uint16_t*)((char*)d_ws + OFF_MHIT);
        float*    num  = (float*)((char*)d_ws + OFF_NUM);
        float*    den  = (float*)((char*)d_ws + OFF_DEN);
        convert_kernel<<<NMEM / 64, 256, 0, stream>>>(memory, mhi, mlo, mhit);
        attn_kernel<<<QROWS * NCHUNK, 256, 0, stream>>>(query, mhi, mlo, mhit, num, den);
        reduce_kernel<<<NQ_TOT * DIM / 256, 256, 0, stream>>>(num, den, out);
    } else {
        sparse_attn_fp32<<<NQ_TOT / FTQ, FBLOCK, 0, stream>>>(query, memory, out);
    }
}

// Round 4
// 193.780 us; speedup vs baseline: 1.5829x; 1.5829x over previous
//
#include <hip/hip_runtime.h>
#include <stdint.h>

#define DIM     128
#define NMEM    16384
#define NQ_TOT  2048
#define TQ      64                    // queries per WG
#define TN      64                    // mem rows per iter
#define CHUNKS  16
#define CHUNK_ROWS (NMEM / CHUNKS)    // 1024
#define ITERS   (CHUNK_ROWS / TN)     // 16
#define QROWS   (NQ_TOT / TQ)         // 32
#define SHIFT   30.0f

typedef short s8v __attribute__((ext_vector_type(8)));
typedef float f4v __attribute__((ext_vector_type(4)));

// ---- workspace layout (bytes) ----
#define OFF_MHI   0u
#define OFF_MLO   (4u << 20)
#define OFF_MHIT  (8u << 20)
#define OFF_NUM   (12u << 20)
#define OFF_DEN   (OFF_NUM + (CHUNKS * NQ_TOT * DIM * 4u))  // 28 MB
#define WS_NEED   ((size_t)(OFF_DEN + CHUNKS * NQ_TOT * 4u))

__device__ __forceinline__ uint16_t f2bf(float x) {
    uint32_t u = __float_as_uint(x);
    uint32_t r = u + 0x7fffu + ((u >> 16) & 1u);   // RNE
    return (uint16_t)(r >> 16);
}
__device__ __forceinline__ float bf2f(uint16_t h) {
    return __uint_as_float(((uint32_t)h) << 16);
}

// ============ pre-pass: fp32 memory -> bf16 hi/lo + transposed hi ============
__global__ __launch_bounds__(256)
void convert_kernel(const float* __restrict__ mem, uint16_t* __restrict__ mhi,
                    uint16_t* __restrict__ mlo, uint16_t* __restrict__ mhit) {
    __shared__ uint16_t T[DIM * 64];           // [d][n] 16 KB
    const int b  = blockIdx.x;                 // 256 blocks x 64 rows
    const int t  = threadIdx.x;
    const int n0 = b * 64;
    #pragma unroll
    for (int k = 0; k < 8; ++k) {
        const int idx4 = t + k * 256;          // float4 index within 64x128 tile
        const int r    = idx4 >> 5;
        const int c4   = idx4 & 31;
        const float4 v = ((const float4*)(mem + (size_t)(n0 + r) * DIM))[c4];
        const uint16_t h0 = f2bf(v.x), h1 = f2bf(v.y), h2 = f2bf(v.z), h3 = f2bf(v.w);
        *(ushort4*)&mhi[(size_t)(n0 + r) * DIM + c4 * 4] = make_ushort4(h0, h1, h2, h3);
        *(ushort4*)&mlo[(size_t)(n0 + r) * DIM + c4 * 4] =
            make_ushort4(f2bf(v.x - bf2f(h0)), f2bf(v.y - bf2f(h1)),
                         f2bf(v.z - bf2f(h2)), f2bf(v.w - bf2f(h3)));
        T[(c4 * 4 + 0) * 64 + r] = h0;
        T[(c4 * 4 + 1) * 64 + r] = h1;
        T[(c4 * 4 + 2) * 64 + r] = h2;
        T[(c4 * 4 + 3) * 64 + r] = h3;
    }
    __syncthreads();
    {
        const int d = t >> 1, h = t & 1;
        ushort4* dst = (ushort4*)&mhit[(size_t)d * NMEM + n0 + h * 32];
        const ushort4* src = (const ushort4*)&T[d * 64 + h * 32];
        #pragma unroll
        for (int k = 0; k < 8; ++k) dst[k] = src[k];
    }
}

// ============ main attention: MFMA QK^T -> exp -> MFMA PV (additive chunks) ==
// Block mapping: xcd = bx&7 (round-robin dispatch); each XCD owns exactly 2
// chunks -> per-XCD L2 working set = 2 x 768KB = 1.5MB < 4MB, so all M
// re-reads are L2 hits instead of LLC (round-3 lesson: LLC-BW-bound at
// ~2.5 TB/s when the per-XCD working set is 12MB).
__global__ __launch_bounds__(256, 2)
void attn_kernel(const float* __restrict__ query,
                 const uint16_t* __restrict__ mhi,
                 const uint16_t* __restrict__ mlo,
                 const uint16_t* __restrict__ mhit,
                 float* __restrict__ num, float* __restrict__ den) {
    __shared__ uint16_t MsHi[TN * DIM];  // [r][c'^swz] 16 KB
    __shared__ uint16_t MsLo[TN * DIM];  // 16 KB
    __shared__ uint16_t MsT [DIM * TN];  // [d][c'^swz] 16 KB
    __shared__ uint16_t Ps  [TQ * TN];   // [q][c'^swz] 8 KB
    __shared__ float    Red [4 * TQ];

    const int tid   = threadIdx.x;
    const int wv    = tid >> 6;
    const int lane  = tid & 63;
    const int l16   = lane & 15;
    const int quad  = lane >> 4;
    const int bx    = blockIdx.x;
    // ---- XCD-affinity swizzle: chunk pinned to XCD ----
    const int xcd   = bx & 7;
    const int j     = bx >> 3;                 // 0..63
    const int chunk = xcd * 2 + (j & 1);       // 2 chunks per XCD
    const int qrow  = j >> 1;                  // 0..31
    const int q0    = qrow * TQ;
    const int nbase = chunk * CHUNK_ROWS;

    // ---- Q fragments (hi/lo) live in registers for the whole kernel ----
    s8v qh[4][4], ql[4][4];
    #pragma unroll
    for (int qt = 0; qt < 4; ++qt) {
        const float* qp = query + (size_t)(q0 + qt * 16 + l16) * DIM + quad * 8;
        #pragma unroll
        for (int ks = 0; ks < 4; ++ks) {
            const float4 a = *(const float4*)(qp + ks * 32);
            const float4 b = *(const float4*)(qp + ks * 32 + 4);
            const float f[8] = {a.x, a.y, a.z, a.w, b.x, b.y, b.z, b.w};
            s8v vh, vl;
            #pragma unroll
            for (int jj = 0; jj < 8; ++jj) {
                const uint16_t hh = f2bf(f[jj]);
                vh[jj] = (short)hh;
                vl[jj] = (short)f2bf(f[jj] - bf2f(hh));
            }
            qh[qt][ks] = vh;
            ql[qt][ks] = vl;
        }
    }

    f4v oacc[4][2];
    float dacc[16];
    #pragma unroll
    for (int qt = 0; qt < 4; ++qt)
        #pragma unroll
        for (int dt = 0; dt < 2; ++dt)
            oacc[qt][dt] = (f4v){0.f, 0.f, 0.f, 0.f};
    #pragma unroll
    for (int i = 0; i < 16; ++i) dacc[i] = 0.f;

    for (int it = 0; it < ITERS; ++it) {
        const int n0 = nbase + it * TN;
        __syncthreads();                       // prev iter finished with tiles

        // ---- stage: 48 x 16B-wide global_load_lds, 12 per wave ----
        #pragma unroll
        for (int ii = 0; ii < 12; ++ii) {
            const int id = wv * 12 + ii;
            if (id < 16) {
                const int s = id * 64 + lane;
                const int r = s >> 4, c = (s & 15) ^ (r & 7);
                const uint16_t* g = mhi + (size_t)(n0 + r) * DIM + c * 8;
                __builtin_amdgcn_global_load_lds(
                    (const __attribute__((address_space(1))) void*)g,
                    (__attribute__((address_space(3))) void*)&MsHi[id * 512], 16, 0, 0);
            } else if (id < 32) {
                const int jj = id - 16;
                const int s = jj * 64 + lane;
                const int r = s >> 4, c = (s & 15) ^ (r & 7);
                const uint16_t* g = mlo + (size_t)(n0 + r) * DIM + c * 8;
                __builtin_amdgcn_global_load_lds(
                    (const __attribute__((address_space(1))) void*)g,
                    (__attribute__((address_space(3))) void*)&MsLo[jj * 512], 16, 0, 0);
            } else {
                const int jj = id - 32;
                const int s = jj * 64 + lane;
                const int d = s >> 3, c = (s & 7) ^ (d & 7);
                const uint16_t* g = mhit + (size_t)d * NMEM + n0 + c * 8;
                __builtin_amdgcn_global_load_lds(
                    (const __attribute__((address_space(1))) void*)g,
                    (__attribute__((address_space(3))) void*)&MsT[jj * 512], 16, 0, 0);
            }
        }
        __syncthreads();                       // vmcnt(0) drain + visibility

        // ---- QK^T: wave wv owns rows [wv*16, wv*16+16) ----
        f4v sacc[4];
        #pragma unroll
        for (int qt = 0; qt < 4; ++qt) sacc[qt] = (f4v){0.f, 0.f, 0.f, 0.f};
        const int r   = wv * 16 + l16;
        const int rsw = r & 7;
        #pragma unroll
        for (int ks = 0; ks < 4; ++ks) {
            const int c = ks * 4 + quad;
            const s8v bh = *(const s8v*)&MsHi[r * DIM + ((c ^ rsw) << 3)];
            const s8v bl = *(const s8v*)&MsLo[r * DIM + ((c ^ rsw) << 3)];
            #pragma unroll
            for (int qt = 0; qt < 4; ++qt) {
                sacc[qt] = __builtin_amdgcn_mfma_f32_16x16x32_bf16(qh[qt][ks], bh, sacc[qt], 0, 0, 0);
                sacc[qt] = __builtin_amdgcn_mfma_f32_16x16x32_bf16(ql[qt][ks], bh, sacc[qt], 0, 0, 0);
                sacc[qt] = __builtin_amdgcn_mfma_f32_16x16x32_bf16(qh[qt][ks], bl, sacc[qt], 0, 0, 0);
            }
        }

        // ---- exp + P write (bf16) + denominator accumulation (fp32) ----
        const int ntile = wv * 16 + l16;
        const int nc = ntile >> 3, nlo = ntile & 7;
        #pragma unroll
        for (int qt = 0; qt < 4; ++qt)
            #pragma unroll
            for (int rg = 0; rg < 4; ++rg) {
                const float p = __expf(sacc[qt][rg] - SHIFT);
                const uint16_t pb = f2bf(p);
                dacc[qt * 4 + rg] += bf2f(pb);   // num/den consistent
                const int qloc = qt * 16 + quad * 4 + rg;
                const int swz  = (qloc ^ (qloc >> 3)) & 7;
                Ps[qloc * TN + ((nc ^ swz) << 3) + nlo] = pb;
            }
        __syncthreads();                       // P visible to all waves

        // ---- PV: wave wv owns d in [wv*32, wv*32+32) ----
        #pragma unroll
        for (int ks = 0; ks < 2; ++ks) {
            s8v bt[2];
            #pragma unroll
            for (int dt = 0; dt < 2; ++dt) {
                const int d = wv * 32 + dt * 16 + l16;
                const int c = ks * 4 + quad;
                bt[dt] = *(const s8v*)&MsT[d * TN + ((c ^ (d & 7)) << 3)];
            }
            #pragma unroll
            for (int qt = 0; qt < 4; ++qt) {
                const int q   = qt * 16 + l16;
                const int swz = (q ^ (q >> 3)) & 7;
                const int c   = ks * 4 + quad;
                const s8v pf  = *(const s8v*)&Ps[q * TN + ((c ^ swz) << 3)];
                oacc[qt][0] = __builtin_amdgcn_mfma_f32_16x16x32_bf16(pf, bt[0], oacc[qt][0], 0, 0, 0);
                oacc[qt][1] = __builtin_amdgcn_mfma_f32_16x16x32_bf16(pf, bt[1], oacc[qt][1], 0, 0, 0);
            }
        }
    }

    // ---- epilogue: denominator cross-lane + cross-wave reduce ----
    #pragma unroll
    for (int m = 1; m <= 8; m <<= 1)
        #pragma unroll
        for (int i = 0; i < 16; ++i)
            dacc[i] += __shfl_xor(dacc[i], m, 64);
    if (l16 == 0) {
        #pragma unroll
        for (int qt = 0; qt < 4; ++qt)
            #pragma unroll
            for (int rg = 0; rg < 4; ++rg)
                Red[wv * TQ + qt * 16 + quad * 4 + rg] = dacc[qt * 4 + rg];
    }
    __syncthreads();
    if (tid < TQ) {
        const float dsum = Red[tid] + Red[TQ + tid] + Red[2 * TQ + tid] + Red[3 * TQ + tid];
        den[chunk * NQ_TOT + q0 + tid] = dsum;
    }
    // ---- numerator partial stores ----
    #pragma unroll
    for (int qt = 0; qt < 4; ++qt)
        #pragma unroll
        for (int dt = 0; dt < 2; ++dt)
            #pragma unroll
            for (int rg = 0; rg < 4; ++rg) {
                const int q = q0 + qt * 16 + quad * 4 + rg;
                const int d = wv * 32 + dt * 16 + l16;
                num[(size_t)chunk * NQ_TOT * DIM + (size_t)q * DIM + d] = oacc[qt][dt][rg];
            }
}

// ============ final reduce over chunks + normalize ============
__global__ __launch_bounds__(256)
void reduce_kernel(const float* __restrict__ num, const float* __restrict__ den,
                   float* __restrict__ out) {
    const int idx = blockIdx.x * 256 + threadIdx.x;   // 262144
    const int q = idx >> 7;
    float ns = 0.f, ds = 0.f;
    #pragma unroll
    for (int c = 0; c < CHUNKS; ++c) {
        ns += num[(size_t)c * NQ_TOT * DIM + idx];
        ds += den[c * NQ_TOT + q];
    }
    out[idx] = ns / ds;
}

// ============ fallback (round-1 fp32 kernel) if ws too small ============
#define FTQ 8
#define FTN 64
#define FNTILES (NMEM / FTN)
#define FBLOCK 512
#define MPAD 132
#define PPAD 68

__global__ __launch_bounds__(FBLOCK, 2)
void sparse_attn_fp32(const float* __restrict__ query,
                      const float* __restrict__ memory,
                      float* __restrict__ out) {
    __shared__ float Qs[FTQ * MPAD];
    __shared__ float Ms[FTN * MPAD];
    __shared__ float Psh[FTQ * PPAD];
    __shared__ float Rd[FTQ * PPAD];
    const int tid = threadIdx.x;
    const int q = tid & 7, rest = tid >> 3;
    const int ng = rest, dg = rest & 31, half = rest >> 5;
    const long q0 = (long)blockIdx.x * FTQ;
    if (tid < FTQ * DIM / 4) {
        const float4 v = ((const float4*)(query + q0 * DIM))[tid];
        *(float4*)&Qs[(tid >> 5) * MPAD + ((tid & 31) << 2)] = v;
    }
    float4 pf[4];
    {
        const float4* msrc = (const float4*)memory;
        #pragma unroll
        for (int k = 0; k < 4; ++k) pf[k] = msrc[tid + k * FBLOCK];
    }
    float4 acc = make_float4(0.f, 0.f, 0.f, 0.f);
    float l_part = 0.f;
    for (int t = 0; t < FNTILES; ++t) {
        __syncthreads();
        #pragma unroll
        for (int k = 0; k < 4; ++k) {
            const int f4 = tid + k * FBLOCK;
            *(float4*)&Ms[(f4 >> 5) * MPAD + ((f4 & 31) << 2)] = pf[k];
        }
        __syncthreads();
        if (t + 1 < FNTILES) {
            const float4* msrc = (const float4*)(memory + (long)(t + 1) * FTN * DIM);
            #pragma unroll
            for (int k = 0; k < 4; ++k) pf[k] = msrc[tid + k * FBLOCK];
        }
        float4 s4 = make_float4(0.f, 0.f, 0.f, 0.f);
        const float* qrow = &Qs[q * MPAD];
        const float* mrow = &Ms[ng * MPAD];
        #pragma unroll
        for (int jj = 0; jj < 32; ++jj) {
            const float4 qv = *(const float4*)&qrow[jj * 4];
            const float4 mv = *(const float4*)&mrow[jj * 4];
            s4.x += qv.x * mv.x; s4.y += qv.y * mv.y;
            s4.z += qv.z * mv.z; s4.w += qv.w * mv.w;
        }
        const float p = __expf(((s4.x + s4.y) + (s4.z + s4.w)) - SHIFT);
        Psh[q * PPAD + ng] = p;
        l_part += p;
        __syncthreads();
        #pragma unroll
        for (int n = 0; n < 32; ++n) {
            const int nn = half * 32 + n;
            const float pw = Psh[q * PPAD + nn];
            const float4 mv = *(const float4*)&Ms[nn * MPAD + dg * 4];
            acc.x += pw * mv.x; acc.y += pw * mv.y;
            acc.z += pw * mv.z; acc.w += pw * mv.w;
        }
    }
    __syncthreads();
    Rd[q * PPAD + rest] = l_part;
    if (half == 1) *(float4*)&Ms[q * MPAD + dg * 4] = acc;
    __syncthreads();
    if (half == 0) {
        const float4 o2 = *(const float4*)&Ms[q * MPAD + dg * 4];
        float l = 0.f;
        #pragma unroll 8
        for (int i = 0; i < 64; ++i) l += Rd[q * PPAD + i];
        const float inv = 1.0f / l;
        float4 o;
        o.x = (acc.x + o2.x) * inv; o.y = (acc.y + o2.y) * inv;
        o.z = (acc.z + o2.z) * inv; o.w = (acc.w + o2.w) * inv;
        *(float4*)(out + (q0 + q) * DIM + dg * 4) = o;
    }
}

extern "C" void kernel_launch(void* const* d_in, const int* in_sizes, int n_in,
                              void* d_out, int out_size, void* d_ws, size_t ws_size,
                              hipStream_t stream) {
    const float* query  = (const float*)d_in[0];
    const float* memory = (const float*)d_in[1];
    float* out = (float*)d_out;
    if (ws_size >= WS_NEED) {
        uint16_t* mhi  = (uint16_t*)((char*)d_ws + OFF_MHI);
        uint16_t* mlo  = (uint16_t*)((char*)d_ws + OFF_MLO);
        uint16_t* mhit = (uint16_t*)((char*)d_ws + OFF_MHIT);
        float*    num  = (float*)((char*)d_ws + OFF_NUM);
        float*    den  = (float*)((char*)d_ws + OFF_DEN);
        convert_kernel<<<NMEM / 64, 256, 0, stream>>>(memory, mhi, mlo, mhit);
        attn_kernel<<<QROWS * CHUNKS, 256, 0, stream>>>(query, mhi, mlo, mhit, num, den);
        reduce_kernel<<<NQ_TOT * DIM / 256, 256, 0, stream>>>(num, den, out);
    } else {
        sparse_attn_fp32<<<NQ_TOT / FTQ, FBLOCK, 0, stream>>>(query, memory, out);
    }
}